// Round 12
// baseline (87.042 us; speedup 1.0000x reference)
//
#include <hip/hip_runtime.h>
#include <hip/hip_bf16.h>
#include <math.h>

#define C 8
#define K 128
#define S 64
#define L 2048
#define NB 64
#define W (L - S + 1)   // 1985
#define TW 128
#define NTW 16
#define XCS 208         // xcop stride shorts: 104 dw = 8 banks mod 32 -> conflict-free b128
#define XFS 200         // fp32 x scratch stride (192 data + 8 zero pad)

typedef __attribute__((ext_vector_type(8))) short bf16x8;
typedef __attribute__((ext_vector_type(4))) float f32x4;

__device__ __forceinline__ unsigned short f2bf(float f) {
  unsigned int u = __float_as_uint(f);
  u += 0x7FFFu + ((u >> 16) & 1u);   // RNE
  return (unsigned short)(u >> 16);
}

// packed f32x2 -> bf16x2 (v_cvt_pk_bf16_f32 on gfx950)
__device__ __forceinline__ unsigned int pkbf(float a, float b) {
  __hip_bfloat162 h = __float22bfloat162_rn(make_float2(a, b));
  return *reinterpret_cast<unsigned int*>(&h);
}

// VALU-only sqrt (x >= 0): rsqrt bit-hack + 1 Newton + mul. ~7 full-rate
// VALU instrs (~14 cyc/wave) vs v_sqrt's ~16 cyc on the quarter-rate trans
// unit. Rel err <= ~0.2% — d2 here is O(100) (64-term z-normed distances,
// never near 0), so abs err per term ~0.02 on values ~12. Purpose: feed the
// MAIN VALU with half the sqrt stream while the trans unit chews the other
// half (m114-style cross-unit concurrency).
__device__ __forceinline__ float fsqrt_fast(float x) {
  float y = __uint_as_float(0x5f3759dfu - (__float_as_uint(x) >> 1));
  y = y * fmaf(-0.5f * x * y, y, 1.5f);   // 1 NR on rsqrt
  return x * y;
}

// prep: z-normalize shapelets -> bf16 * (-2), B-fragment order grouped by
// CHANNEL (16 KB contiguous per c, both 64k halves inside); init out to +inf.
// sum(z^2) == S == 64 exactly (population z-norm) -> no per-k sqs needed.
__global__ __launch_bounds__(256) void prep_kernel(const float* __restrict__ sh,
                                                   unsigned short* __restrict__ shzB,
                                                   float* __restrict__ out) {
  int tid = blockIdx.x * 256 + threadIdx.x;
  if (tid < NB * K) out[tid] = __int_as_float(0x7F800000);
  int gid = blockIdx.x * 4 + (threadIdx.x >> 6);  // c*K + k
  int lane = threadIdx.x & 63;                    // = s
  float v = sh[(size_t)gid * S + lane];
  float s1 = v, s2 = v * v;
#pragma unroll
  for (int off = 32; off > 0; off >>= 1) {
    s1 += __shfl_down(s1, off);
    s2 += __shfl_down(s2, off);
  }
  s1 = __shfl(s1, 0);
  s2 = __shfl(s2, 0);
  float mu = s1 * (1.0f / S);
  float sd = sqrtf(fmaxf(s2 * (1.0f / S) - mu * mu, 0.0f));
  float z = (v - mu) / sd;
  int c = gid >> 7, k = gid & (K - 1), s = lane;
  // layout: [c][k>>6][((k>>4)&3)*2 + (s>>5)][lane'=((s>>3)&3)*16+(k&15)][s&7]
  int idx = c * 8192 + (k >> 6) * 4096 + ((((k >> 4) & 3) * 2) + (s >> 5)) * 512 +
            ((((s >> 3) & 3) * 16 + (k & 15)) * 8) + (s & 7);
  shzB[idx] = f2bf(-2.0f * z);   // bake the -2 of d2 = (sqx + 64) - 2*cross
}

// One wt-subtile: 8 MFMAs (4 kt x 2 halves) into P[0..3] (all indices literal)
#define WT_COMPUTE(WT, P)                                                     \
  {                                                                           \
    bf16x8 x0 = *(const bf16x8*)(xc + abase + (WT) * 16);                     \
    bf16x8 x1 = *(const bf16x8*)(xc + abase + (WT) * 16 + 32);                \
    f32x4 ai = *(const f32x4*)&sqx[c][wgrp * 64 + (WT) * 16 + quad * 4];      \
    P[0] = __builtin_amdgcn_mfma_f32_16x16x32_bf16(x0, Bc[0], ai, 0, 0, 0);   \
    P[1] = __builtin_amdgcn_mfma_f32_16x16x32_bf16(x0, Bc[2], ai, 0, 0, 0);   \
    P[2] = __builtin_amdgcn_mfma_f32_16x16x32_bf16(x0, Bc[4], ai, 0, 0, 0);   \
    P[3] = __builtin_amdgcn_mfma_f32_16x16x32_bf16(x0, Bc[6], ai, 0, 0, 0);   \
    P[0] = __builtin_amdgcn_mfma_f32_16x16x32_bf16(x1, Bc[1], P[0], 0, 0, 0); \
    P[1] = __builtin_amdgcn_mfma_f32_16x16x32_bf16(x1, Bc[3], P[1], 0, 0, 0); \
    P[2] = __builtin_amdgcn_mfma_f32_16x16x32_bf16(x1, Bc[5], P[2], 0, 0, 0); \
    P[3] = __builtin_amdgcn_mfma_f32_16x16x32_bf16(x1, Bc[7], P[3], 0, 0, 0); \
  }

// trans epilogue of one wt-subtile, SPLIT across execution units:
// kt 0,1 -> v_sqrt (trans unit, abs is a free input modifier);
// kt 2,3 -> fsqrt_fast (main VALU). Interleaved so both units have
// concurrent work inside the same scheduling window.
#define WT_SQRT(WT, P)                                                        \
  {                                                                           \
    _Pragma("unroll")                                                         \
    for (int i = 0; i < 4; ++i) {                                             \
      dsum[0][WT][i] += __builtin_amdgcn_sqrtf(__builtin_fabsf(P[0][i]));     \
      dsum[2][WT][i] += fsqrt_fast(__builtin_fabsf(P[2][i]));                 \
      dsum[1][WT][i] += __builtin_amdgcn_sqrtf(__builtin_fabsf(P[1][i]));     \
      dsum[3][WT][i] += fsqrt_fast(__builtin_fabsf(P[3][i]));                 \
    }                                                                         \
  }

// main: block = 128w x 128k, 256 threads = 4 waves, wave tile 64w x 64k.
// Skeleton = R7/R11, the session's reproducible best (main ~39us): wt-level
// pA/pB alternation (32 regs in flight), channel-ring stagger, barrier-free
// loop, B from L2-resident global. R12 changes ONE thing: the 130M-sqrt
// stream is split 50/50 between the quarter-rate trans unit (v_sqrt, ~16cyc)
// and the full-rate main VALU (Newton rsqrt hack, ~7 instrs ~14cyc) — if the
// two units execute concurrently (m114 showed MFMA||VALU does), effective
// sqrt throughput nearly doubles. Bounded downside: if trans is not a
// separate unit, VALU path ~= trans path and the change is neutral.
// Accuracy: 1-NR rel err <=0.2% on d2~O(100) -> absmax +<=0.1 (vs thr 1.69).
// Tripwire: WRITE ~1MB, FETCH ~3.6MB (else spill -> void).
__global__ __launch_bounds__(256, 3) void main_kernel(const float* __restrict__ x,
                                                      const unsigned short* __restrict__ shzB,
                                                      int* __restrict__ out) {
  __shared__ __align__(16) unsigned short xcop[C][8][XCS]; // 26 KB: 8 shifted copies
  __shared__ __align__(16) float sqx[C][TW];               // 4 KB (pre-biased +64)
  __shared__ __align__(16) float xf[C][XFS];               // 6.4 KB fp32 x scratch

  const int t = threadIdx.x;
  const int lane = t & 63;
  const int wave = t >> 6;     // 0..3
  const int wgrp = wave & 1;   // w-offset 64
  const int kgrp = wave >> 1;  // 0..1 : k-offset 64*kgrp
  const int col = lane & 15;
  const int quad = lane >> 4;
  const int n = blockIdx.y;
  const int w0 = blockIdx.x * TW;
  const float* xn = x + (size_t)n * C * L;
  // this wave's B-fragment stream: 8 x 1KB contiguous chunks per channel
  const unsigned short* bw = shzB + kgrp * 4096 + lane * 8;
  // phase-stagger start channel (wave-uniform SGPR; decorrelates waves/blocks)
  const int cbase = (2 * wave + blockIdx.x + blockIdx.y) & 7;

  // ---- stage fp32 x segment into xf (2 ch/wave, float4/lane) ----
  float* xfp = &xf[0][0];
#pragma unroll
  for (int cc = 0; cc < 2; ++cc) {
    const int c = wave * 2 + cc;
    const int e = lane * 4;
    float4 v; v.x = v.y = v.z = v.w = 0.0f;
    if (lane < 48) {
      int g = w0 + e;
      if (g + 3 < L) {
        v = *(const float4*)(xn + c * L + g);
      } else {  // last w-tile tail; feeds masked windows only
        v.x = (g + 0 < L) ? xn[c * L + g + 0] : 0.0f;
        v.y = (g + 1 < L) ? xn[c * L + g + 1] : 0.0f;
        v.z = (g + 2 < L) ? xn[c * L + g + 2] : 0.0f;
        v.w = (g + 3 < L) ? xn[c * L + g + 3] : 0.0f;
      }
    }
    if (lane < 50) *(float4*)&xfp[c * XFS + e] = v;   // lanes 48,49 zero-pad tail
  }
  __syncthreads();

  // ---- build 8 shifted bf16 copies (2 ch/wave; r=lane>>3; 12 dwords/lane/ch) ----
#pragma unroll
  for (int cc = 0; cc < 2; ++cc) {
    const int cb = wave * 2 + cc;
    const int rb = lane >> 3;         // 0..7
    const int c8 = lane & 7;
    const float* xr = xfp + cb * XFS;
#pragma unroll
    for (int j = 0; j < 12; ++j) {
      int i = (c8 + j * 8) * 2;       // 0..190 even
      *(unsigned int*)&xcop[cb][rb][i] = pkbf(xr[i + rb], xr[i + rb + 1]);
    }
  }
  // ---- sliding-window fp32 sqx (+64 bias = sum(z^2)): 2 ch/wave, 2 w/lane ----
#pragma unroll
  for (int cc = 0; cc < 2; ++cc) {
    const int c = wave * 2 + cc, wl = lane * 2;
    const float* xr = xfp + c * XFS;
    float p0 = 0.f, p1 = 0.f, p2 = 0.f, p3 = 0.f;
#pragma unroll
    for (int si = 0; si < S; si += 4) {
      float v0 = xr[wl + si], v1 = xr[wl + si + 1], v2 = xr[wl + si + 2], v3 = xr[wl + si + 3];
      p0 = fmaf(v0, v0, p0); p1 = fmaf(v1, v1, p1);
      p2 = fmaf(v2, v2, p2); p3 = fmaf(v3, v3, p3);
    }
    float s0 = 64.0f + (p0 + p1) + (p2 + p3);
    sqx[c][wl] = s0;
    float a = xr[wl + S], b = xr[wl];
    sqx[c][wl + 1] = s0 + a * a - b * b;
  }
  __syncthreads();  // xcop + sqx ready; NO barriers after this point

  const f32x4 z4 = {0.0f, 0.0f, 0.0f, 0.0f};
  f32x4 dsum[4][4];   // [ktile][wtile]
#pragma unroll
  for (int kt = 0; kt < 4; ++kt)
#pragma unroll
    for (int wt = 0; wt < 4; ++wt) dsum[kt][wt] = z4;

  const int r8 = col & 7;
  const int abase = wgrp * 64 + (col - r8) + quad * 8;  // multiple of 8 -> b128 aligned

  for (int ci = 0; ci < C; ++ci) {
    const int c = (cbase + ci) & 7;   // wave-uniform (SGPR arithmetic)

    // B fragments for this channel: 8 coalesced dwordx4 from L1/L2
    bf16x8 Bc[8];
#pragma unroll
    for (int i = 0; i < 8; ++i)
      Bc[i] = *(const bf16x8*)(bw + c * 8192 + i * 512);

    const unsigned short* xc = &xcop[c][r8][0];

    // wt-granularity alternation: MFMA(wt+1) drains while sqrt(wt) runs.
    f32x4 pA[4], pB[4];
    WT_COMPUTE(0, pA)
    WT_COMPUTE(1, pB)
    WT_SQRT(0, pA)
    WT_COMPUTE(2, pA)
    WT_SQRT(1, pB)
    WT_COMPUTE(3, pB)
    WT_SQRT(2, pA)
    WT_SQRT(3, pB)
  }

  // min over w (regs -> quad shuffles), one atomicMin per (k-tile, lane col)
  const float INF = __int_as_float(0x7F800000);
  const int wbase = w0 + wgrp * 64;
#pragma unroll
  for (int kt = 0; kt < 4; ++kt) {
    float mv = INF;
#pragma unroll
    for (int wt = 0; wt < 4; ++wt)
#pragma unroll
      for (int i = 0; i < 4; ++i) {
        int w = wbase + wt * 16 + quad * 4 + i;
        mv = (w < W) ? fminf(mv, dsum[kt][wt][i]) : mv;
      }
    mv = fminf(mv, __shfl_xor(mv, 16));
    mv = fminf(mv, __shfl_xor(mv, 32));
    if (quad == 0)
      atomicMin(&out[n * K + kgrp * 64 + kt * 16 + col], __float_as_int(mv));
  }
}

extern "C" void kernel_launch(void* const* d_in, const int* in_sizes, int n_in,
                              void* d_out, int out_size, void* d_ws, size_t ws_size,
                              hipStream_t stream) {
  const float* x = (const float*)d_in[0];    // (64, 8, 2048) fp32
  const float* sh = (const float*)d_in[1];   // (8, 128, 64) fp32
  float* out = (float*)d_out;                // (64, 1, 128) fp32
  unsigned short* shzB = (unsigned short*)d_ws;  // 128 KB bf16 B-frag layout (scaled -2)

  prep_kernel<<<256, 256, 0, stream>>>(sh, shzB, out);
  main_kernel<<<dim3(NTW, NB), 256, 0, stream>>>(x, shzB, (int*)out);
}

// Round 13
// 82.270 us; speedup vs baseline: 1.0580x; 1.0580x over previous
//
#include <hip/hip_runtime.h>
#include <hip/hip_bf16.h>
#include <math.h>

#define C 8
#define K 128
#define S 64
#define L 2048
#define NB 64
#define W (L - S + 1)   // 1985
#define TW 128
#define NTW 16
#define XCS 208         // xcop stride shorts: 104 dw = 8 banks mod 32 -> conflict-free b128
#define XFS 200         // fp32 x scratch stride (192 data + 8 zero pad)

typedef __attribute__((ext_vector_type(8))) short bf16x8;
typedef __attribute__((ext_vector_type(4))) float f32x4;

__device__ __forceinline__ unsigned short f2bf(float f) {
  unsigned int u = __float_as_uint(f);
  u += 0x7FFFu + ((u >> 16) & 1u);   // RNE
  return (unsigned short)(u >> 16);
}

// packed f32x2 -> bf16x2 (v_cvt_pk_bf16_f32 on gfx950)
__device__ __forceinline__ unsigned int pkbf(float a, float b) {
  __hip_bfloat162 h = __float22bfloat162_rn(make_float2(a, b));
  return *reinterpret_cast<unsigned int*>(&h);
}

// prep: z-normalize shapelets -> bf16 * (-2), B-fragment order grouped by
// CHANNEL (16 KB contiguous per c, both 64k halves inside); init out to +inf.
// sum(z^2) == S == 64 exactly (population z-norm) -> no per-k sqs needed.
__global__ __launch_bounds__(256) void prep_kernel(const float* __restrict__ sh,
                                                   unsigned short* __restrict__ shzB,
                                                   float* __restrict__ out) {
  int tid = blockIdx.x * 256 + threadIdx.x;
  if (tid < NB * K) out[tid] = __int_as_float(0x7F800000);
  int gid = blockIdx.x * 4 + (threadIdx.x >> 6);  // c*K + k
  int lane = threadIdx.x & 63;                    // = s
  float v = sh[(size_t)gid * S + lane];
  float s1 = v, s2 = v * v;
#pragma unroll
  for (int off = 32; off > 0; off >>= 1) {
    s1 += __shfl_down(s1, off);
    s2 += __shfl_down(s2, off);
  }
  s1 = __shfl(s1, 0);
  s2 = __shfl(s2, 0);
  float mu = s1 * (1.0f / S);
  float sd = sqrtf(fmaxf(s2 * (1.0f / S) - mu * mu, 0.0f));
  float z = (v - mu) / sd;
  int c = gid >> 7, k = gid & (K - 1), s = lane;
  // layout: [c][k>>6][((k>>4)&3)*2 + (s>>5)][lane'=((s>>3)&3)*16+(k&15)][s&7]
  int idx = c * 8192 + (k >> 6) * 4096 + ((((k >> 4) & 3) * 2) + (s >> 5)) * 512 +
            ((((s >> 3) & 3) * 16 + (k & 15)) * 8) + (s & 7);
  shzB[idx] = f2bf(-2.0f * z);   // bake the -2 of d2 = (sqx + 64) - 2*cross
}

// One wt-subtile: 8 MFMAs (4 kt x 2 halves) into P[0..3] (all indices literal)
#define WT_COMPUTE(WT, P)                                                     \
  {                                                                           \
    bf16x8 x0 = *(const bf16x8*)(xc + abase + (WT) * 16);                     \
    bf16x8 x1 = *(const bf16x8*)(xc + abase + (WT) * 16 + 32);                \
    f32x4 ai = *(const f32x4*)&sqx[c][wgrp * 64 + (WT) * 16 + quad * 4];      \
    P[0] = __builtin_amdgcn_mfma_f32_16x16x32_bf16(x0, Bc[0], ai, 0, 0, 0);   \
    P[1] = __builtin_amdgcn_mfma_f32_16x16x32_bf16(x0, Bc[2], ai, 0, 0, 0);   \
    P[2] = __builtin_amdgcn_mfma_f32_16x16x32_bf16(x0, Bc[4], ai, 0, 0, 0);   \
    P[3] = __builtin_amdgcn_mfma_f32_16x16x32_bf16(x0, Bc[6], ai, 0, 0, 0);   \
    P[0] = __builtin_amdgcn_mfma_f32_16x16x32_bf16(x1, Bc[1], P[0], 0, 0, 0); \
    P[1] = __builtin_amdgcn_mfma_f32_16x16x32_bf16(x1, Bc[3], P[1], 0, 0, 0); \
    P[2] = __builtin_amdgcn_mfma_f32_16x16x32_bf16(x1, Bc[5], P[2], 0, 0, 0); \
    P[3] = __builtin_amdgcn_mfma_f32_16x16x32_bf16(x1, Bc[7], P[3], 0, 0, 0); \
  }

// trans epilogue of one wt-subtile (literal WT -> static dsum indexing).
// R12 lesson: v_sqrt shares the VALU issue/execute resource — a Newton/VALU
// "offload" path only ADDS issue work (+6us). Keep the 1-instr v_sqrt form.
#define WT_SQRT(WT, P)                                                        \
  {                                                                           \
    _Pragma("unroll")                                                         \
    for (int i = 0; i < 4; ++i) {                                             \
      dsum[0][WT][i] += __builtin_amdgcn_sqrtf(__builtin_fabsf(P[0][i]));     \
      dsum[1][WT][i] += __builtin_amdgcn_sqrtf(__builtin_fabsf(P[1][i]));     \
      dsum[2][WT][i] += __builtin_amdgcn_sqrtf(__builtin_fabsf(P[2][i]));     \
      dsum[3][WT][i] += __builtin_amdgcn_sqrtf(__builtin_fabsf(P[3][i]));     \
    }                                                                         \
  }

// main: block = 128w x 128k, 256 threads = 4 waves, wave tile 64w x 64k.
// FINAL = exact R7/R11, the session's reproducible best (main ~39us, bench
// ~81.5us). Session ledger of falsified alternatives:
//   R8  64w geometry + tight VGPR cap  -> compiler scratch (64MB fetch)
//   R9  producer/consumer waves        -> 55us (trans needs MANY issuers)
//   R10 512-thread homogeneous         -> partial spill + occupancy quantization
//   R12 sqrt split trans/VALU-Newton   -> +6us (v_sqrt IS VALU work; no
//                                         separate trans pipe to co-feed)
// Standing model: VALU-issue-work bound (~45K cyc/SIMD of sqrt+add) at the
// ~48-55% feed rate that 13 structures bounded; HBM 1.4%, MFMA 15%, LDS
// trivial. Structure: wt-level pA/pB alternation (32 regs in flight) covers
// mfma->sqrt latency; channel-ring stagger (cbase) decorrelates wave phases;
// barrier-free loop; B from L2-resident global; fabs feeds v_sqrt's free
// input modifier.
__global__ __launch_bounds__(256, 3) void main_kernel(const float* __restrict__ x,
                                                      const unsigned short* __restrict__ shzB,
                                                      int* __restrict__ out) {
  __shared__ __align__(16) unsigned short xcop[C][8][XCS]; // 26 KB: 8 shifted copies
  __shared__ __align__(16) float sqx[C][TW];               // 4 KB (pre-biased +64)
  __shared__ __align__(16) float xf[C][XFS];               // 6.4 KB fp32 x scratch

  const int t = threadIdx.x;
  const int lane = t & 63;
  const int wave = t >> 6;     // 0..3
  const int wgrp = wave & 1;   // w-offset 64
  const int kgrp = wave >> 1;  // 0..1 : k-offset 64*kgrp
  const int col = lane & 15;
  const int quad = lane >> 4;
  const int n = blockIdx.y;
  const int w0 = blockIdx.x * TW;
  const float* xn = x + (size_t)n * C * L;
  // this wave's B-fragment stream: 8 x 1KB contiguous chunks per channel
  const unsigned short* bw = shzB + kgrp * 4096 + lane * 8;
  // phase-stagger start channel (wave-uniform SGPR; decorrelates waves/blocks)
  const int cbase = (2 * wave + blockIdx.x + blockIdx.y) & 7;

  // ---- stage fp32 x segment into xf (2 ch/wave, float4/lane) ----
  float* xfp = &xf[0][0];
#pragma unroll
  for (int cc = 0; cc < 2; ++cc) {
    const int c = wave * 2 + cc;
    const int e = lane * 4;
    float4 v; v.x = v.y = v.z = v.w = 0.0f;
    if (lane < 48) {
      int g = w0 + e;
      if (g + 3 < L) {
        v = *(const float4*)(xn + c * L + g);
      } else {  // last w-tile tail; feeds masked windows only
        v.x = (g + 0 < L) ? xn[c * L + g + 0] : 0.0f;
        v.y = (g + 1 < L) ? xn[c * L + g + 1] : 0.0f;
        v.z = (g + 2 < L) ? xn[c * L + g + 2] : 0.0f;
        v.w = (g + 3 < L) ? xn[c * L + g + 3] : 0.0f;
      }
    }
    if (lane < 50) *(float4*)&xfp[c * XFS + e] = v;   // lanes 48,49 zero-pad tail
  }
  __syncthreads();

  // ---- build 8 shifted bf16 copies (2 ch/wave; r=lane>>3; 12 dwords/lane/ch) ----
#pragma unroll
  for (int cc = 0; cc < 2; ++cc) {
    const int cb = wave * 2 + cc;
    const int rb = lane >> 3;         // 0..7
    const int c8 = lane & 7;
    const float* xr = xfp + cb * XFS;
#pragma unroll
    for (int j = 0; j < 12; ++j) {
      int i = (c8 + j * 8) * 2;       // 0..190 even
      *(unsigned int*)&xcop[cb][rb][i] = pkbf(xr[i + rb], xr[i + rb + 1]);
    }
  }
  // ---- sliding-window fp32 sqx (+64 bias = sum(z^2)): 2 ch/wave, 2 w/lane ----
#pragma unroll
  for (int cc = 0; cc < 2; ++cc) {
    const int c = wave * 2 + cc, wl = lane * 2;
    const float* xr = xfp + c * XFS;
    float p0 = 0.f, p1 = 0.f, p2 = 0.f, p3 = 0.f;
#pragma unroll
    for (int si = 0; si < S; si += 4) {
      float v0 = xr[wl + si], v1 = xr[wl + si + 1], v2 = xr[wl + si + 2], v3 = xr[wl + si + 3];
      p0 = fmaf(v0, v0, p0); p1 = fmaf(v1, v1, p1);
      p2 = fmaf(v2, v2, p2); p3 = fmaf(v3, v3, p3);
    }
    float s0 = 64.0f + (p0 + p1) + (p2 + p3);
    sqx[c][wl] = s0;
    float a = xr[wl + S], b = xr[wl];
    sqx[c][wl + 1] = s0 + a * a - b * b;
  }
  __syncthreads();  // xcop + sqx ready; NO barriers after this point

  const f32x4 z4 = {0.0f, 0.0f, 0.0f, 0.0f};
  f32x4 dsum[4][4];   // [ktile][wtile]
#pragma unroll
  for (int kt = 0; kt < 4; ++kt)
#pragma unroll
    for (int wt = 0; wt < 4; ++wt) dsum[kt][wt] = z4;

  const int r8 = col & 7;
  const int abase = wgrp * 64 + (col - r8) + quad * 8;  // multiple of 8 -> b128 aligned

  for (int ci = 0; ci < C; ++ci) {
    const int c = (cbase + ci) & 7;   // wave-uniform (SGPR arithmetic)

    // B fragments for this channel: 8 coalesced dwordx4 from L1/L2
    bf16x8 Bc[8];
#pragma unroll
    for (int i = 0; i < 8; ++i)
      Bc[i] = *(const bf16x8*)(bw + c * 8192 + i * 512);

    const unsigned short* xc = &xcop[c][r8][0];

    // wt-granularity alternation: MFMA(wt+1) drains while sqrt(wt) runs.
    // Only 32 regs of accumulator-in-flight state (vs 64 channel-level).
    f32x4 pA[4], pB[4];
    WT_COMPUTE(0, pA)
    WT_COMPUTE(1, pB)
    WT_SQRT(0, pA)
    WT_COMPUTE(2, pA)
    WT_SQRT(1, pB)
    WT_COMPUTE(3, pB)
    WT_SQRT(2, pA)
    WT_SQRT(3, pB)
  }

  // min over w (regs -> quad shuffles), one atomicMin per (k-tile, lane col)
  const float INF = __int_as_float(0x7F800000);
  const int wbase = w0 + wgrp * 64;
#pragma unroll
  for (int kt = 0; kt < 4; ++kt) {
    float mv = INF;
#pragma unroll
    for (int wt = 0; wt < 4; ++wt)
#pragma unroll
      for (int i = 0; i < 4; ++i) {
        int w = wbase + wt * 16 + quad * 4 + i;
        mv = (w < W) ? fminf(mv, dsum[kt][wt][i]) : mv;
      }
    mv = fminf(mv, __shfl_xor(mv, 16));
    mv = fminf(mv, __shfl_xor(mv, 32));
    if (quad == 0)
      atomicMin(&out[n * K + kgrp * 64 + kt * 16 + col], __float_as_int(mv));
  }
}

extern "C" void kernel_launch(void* const* d_in, const int* in_sizes, int n_in,
                              void* d_out, int out_size, void* d_ws, size_t ws_size,
                              hipStream_t stream) {
  const float* x = (const float*)d_in[0];    // (64, 8, 2048) fp32
  const float* sh = (const float*)d_in[1];   // (8, 128, 64) fp32
  float* out = (float*)d_out;                // (64, 1, 128) fp32
  unsigned short* shzB = (unsigned short*)d_ws;  // 128 KB bf16 B-frag layout (scaled -2)

  prep_kernel<<<256, 256, 0, stream>>>(sh, shzB, out);
  main_kernel<<<dim3(NTW, NB), 256, 0, stream>>>(x, shzB, (int*)out);
}